// Round 1
// baseline (702.541 us; speedup 1.0000x reference)
//
#include <hip/hip_runtime.h>

#define NN 10000
#define EE 160000
#define NH 4

// ---------------------------------------------------------------- CSR build
__global__ __launch_bounds__(256) void hist_kernel(const int* __restrict__ dst,
                                                   int* __restrict__ counts, int E) {
    int e = blockIdx.x * 256 + threadIdx.x;
    if (e < E) atomicAdd(&counts[dst[e]], 1);
}

__global__ __launch_bounds__(256) void scan_kernel(const int* __restrict__ counts,
                                                   int* __restrict__ off,
                                                   int* __restrict__ cur, int n) {
    __shared__ int part[256];
    int tid = threadIdx.x;
    int chunk = (n + 255) / 256;
    int lo = tid * chunk; if (lo > n) lo = n;
    int hi = lo + chunk;  if (hi > n) hi = n;
    int s = 0;
    for (int i = lo; i < hi; ++i) s += counts[i];
    part[tid] = s;
    __syncthreads();
    for (int o = 1; o < 256; o <<= 1) {
        int v = (tid >= o) ? part[tid - o] : 0;
        __syncthreads();
        part[tid] += v;
        __syncthreads();
    }
    int run = (tid == 0) ? 0 : part[tid - 1];
    for (int i = lo; i < hi; ++i) { off[i] = run; cur[i] = run; run += counts[i]; }
    if (tid == 255) off[n] = part[255];
}

__global__ __launch_bounds__(256) void fill_kernel(const int* __restrict__ src,
                                                   const int* __restrict__ dst,
                                                   int* __restrict__ cur,
                                                   int* __restrict__ ssrc,
                                                   int* __restrict__ poe, int E) {
    int e = blockIdx.x * 256 + threadIdx.x;
    if (e < E) {
        int p = atomicAdd(&cur[dst[e]], 1);
        ssrc[p] = src[e];
        poe[e] = p;
    }
}

// ---------------------------------------------------------------- fp32 GEMM
// C[M,Ncols] = A[M,K] @ B[K,Ncols]; Ncols % 64 == 0, K % 16 == 0, M guarded.
__global__ __launch_bounds__(256) void gemm_f32(const float* __restrict__ A,
                                                const float* __restrict__ B,
                                                float* __restrict__ C,
                                                int M, int Ncols, int K) {
    __shared__ float As[16][65];  // As[k][m], +1 pad kills 16-way write conflict
    __shared__ float Bs[16][64];  // Bs[k][n]
    int tid = threadIdx.x;
    int tx = tid & 15, ty = tid >> 4;
    int m0 = blockIdx.y * 64, n0 = blockIdx.x * 64;
    float acc[4][4] = {};
    for (int k0 = 0; k0 < K; k0 += 16) {
        #pragma unroll
        for (int j = 0; j < 4; ++j) {
            int li = tid + 256 * j;            // 0..1023
            int mm = li >> 4, kk = li & 15;    // A[m0+mm][k0+kk]
            float a = 0.f;
            int gm = m0 + mm;
            if (gm < M) a = A[(size_t)gm * K + k0 + kk];
            As[kk][mm] = a;
            int nn = li & 63, kb = li >> 6;    // B[k0+kb][n0+nn]
            Bs[kb][nn] = B[(size_t)(k0 + kb) * Ncols + n0 + nn];
        }
        __syncthreads();
        #pragma unroll
        for (int kk = 0; kk < 16; ++kk) {
            float a[4], b[4];
            #pragma unroll
            for (int i = 0; i < 4; ++i) a[i] = As[kk][ty * 4 + i];
            #pragma unroll
            for (int j = 0; j < 4; ++j) b[j] = Bs[kk][tx * 4 + j];
            #pragma unroll
            for (int i = 0; i < 4; ++i)
                #pragma unroll
                for (int j = 0; j < 4; ++j) acc[i][j] += a[i] * b[j];
        }
        __syncthreads();
    }
    #pragma unroll
    for (int i = 0; i < 4; ++i) {
        int gm = m0 + ty * 4 + i;
        if (gm < M) {
            #pragma unroll
            for (int j = 0; j < 4; ++j)
                C[(size_t)gm * Ncols + n0 + tx * 4 + j] = acc[i][j];
        }
    }
}

// ------------------------------------------------- v[i,h] = sum_d We[i,h,d]*ae[h,d]
__global__ void compute_v(const float* __restrict__ We, const float* __restrict__ ae,
                          float* __restrict__ v) {
    int t = threadIdx.x;        // 256 threads = 64 dims x 4 heads
    int i = t >> 2, h = t & 3;
    const float* w = We + ((size_t)i * 4 + h) * 128;
    const float* a = ae + (size_t)h * 128;
    float s = 0.f;
    for (int d = 0; d < 128; ++d) s += w[d] * a[d];
    v[i * 4 + h] = s;
}

// ------------------------------------------------- el/er: per-(node,head) dots
template <int D>
__global__ __launch_bounds__(256) void eler_kernel(const float* __restrict__ feat,
                                                   const float* __restrict__ al,
                                                   const float* __restrict__ ar,
                                                   float* __restrict__ el,
                                                   float* __restrict__ er) {
    int n = blockIdx.x;
    int h = threadIdx.x >> 6, lane = threadIdx.x & 63;
    const float* f = feat + (size_t)n * (4 * D) + h * D;
    const float* a = al + (size_t)h * D;
    const float* b = ar + (size_t)h * D;
    float s1 = 0.f, s2 = 0.f;
    #pragma unroll
    for (int j = lane; j < D; j += 64) {
        float fv = f[j];
        s1 += fv * a[j];
        s2 += fv * b[j];
    }
    #pragma unroll
    for (int o = 32; o; o >>= 1) {
        s1 += __shfl_down(s1, o);
        s2 += __shfl_down(s2, o);
    }
    if (lane == 0) { el[n * 4 + h] = s1; er[n * 4 + h] = s2; }
}

// ------------------------------------------------- per-edge logits (leaky relu'd)
__global__ __launch_bounds__(256) void edge_logit(const float* __restrict__ el,
                                                  const float* __restrict__ er,
                                                  const int* __restrict__ src,
                                                  const int* __restrict__ dst,
                                                  const float* __restrict__ ef,
                                                  const float* __restrict__ vbuf,
                                                  const int* __restrict__ poe,
                                                  float* __restrict__ lsorted, int E) {
    __shared__ float vs[256];
    if (ef != nullptr) {
        vs[threadIdx.x] = vbuf[threadIdx.x];
        __syncthreads();
    }
    int e = blockIdx.x * 256 + threadIdx.x;
    if (e >= E) return;
    int s = src[e], d = dst[e];
    float4 elv = *(const float4*)(el + (size_t)s * 4);
    float4 erv = *(const float4*)(er + (size_t)d * 4);
    float a0 = elv.x + erv.x, a1 = elv.y + erv.y, a2 = elv.z + erv.z, a3 = elv.w + erv.w;
    if (ef != nullptr) {
        const float4* e4 = (const float4*)(ef + (size_t)e * 64);
        #pragma unroll
        for (int c = 0; c < 16; ++c) {
            float4 x = e4[c];
            int b = c * 16;
            a0 += x.x * vs[b + 0] + x.y * vs[b + 4] + x.z * vs[b + 8] + x.w * vs[b + 12];
            a1 += x.x * vs[b + 1] + x.y * vs[b + 5] + x.z * vs[b + 9] + x.w * vs[b + 13];
            a2 += x.x * vs[b + 2] + x.y * vs[b + 6] + x.z * vs[b + 10] + x.w * vs[b + 14];
            a3 += x.x * vs[b + 3] + x.y * vs[b + 7] + x.z * vs[b + 11] + x.w * vs[b + 15];
        }
    }
    float4 out;
    out.x = a0 > 0.f ? a0 : 0.2f * a0;
    out.y = a1 > 0.f ? a1 : 0.2f * a1;
    out.z = a2 > 0.f ? a2 : 0.2f * a2;
    out.w = a3 > 0.f ? a3 : 0.2f * a3;
    int p = poe[e];
    *(float4*)(lsorted + (size_t)p * 4) = out;
}

// ------------------------------------------------- segment softmax (in place -> exp)
__global__ __launch_bounds__(256) void softmax_seg(const int* __restrict__ off,
                                                   float* __restrict__ lsorted,
                                                   float* __restrict__ den, int n) {
    int t = blockIdx.x * 256 + threadIdx.x;
    if (t >= n * 4) return;
    int nd = t >> 2, h = t & 3;
    int r0 = off[nd], r1 = off[nd + 1];
    float m = -1e30f;
    for (int p = r0; p < r1; ++p) m = fmaxf(m, lsorted[(size_t)p * 4 + h]);
    float s = 0.f;
    for (int p = r0; p < r1; ++p) {
        float ex = __expf(lsorted[(size_t)p * 4 + h] - m);
        lsorted[(size_t)p * 4 + h] = ex;
        s += ex;
    }
    den[t] = s;
}

// --------------------- aggregation + mean over heads + residual add + ReLU
template <int D>
__global__ __launch_bounds__(256) void aggregate(const float* __restrict__ feat,
                                                 const float* __restrict__ exs,
                                                 const int* __restrict__ ssrc,
                                                 const int* __restrict__ off,
                                                 const float* __restrict__ den,
                                                 float* __restrict__ y) {
    __shared__ float red[4 * D];
    int n = blockIdx.x;
    int h = threadIdx.x >> 6, lane = threadIdx.x & 63;
    constexpr int EL = D / 64;
    float acc[EL] = {};
    int r0 = off[n], r1 = off[n + 1];
    for (int p = r0; p < r1; ++p) {
        float w = exs[(size_t)p * 4 + h];
        const float* f = feat + (size_t)ssrc[p] * (4 * D) + h * D + lane;
        #pragma unroll
        for (int j = 0; j < EL; ++j) acc[j] += w * f[64 * j];
    }
    float sc = 0.25f / (den[n * 4 + h] + 1e-9f);
    #pragma unroll
    for (int j = 0; j < EL; ++j) red[h * D + lane + 64 * j] = acc[j] * sc;
    __syncthreads();
    for (int t = threadIdx.x; t < D; t += 256) {
        float s = red[t] + red[D + t] + red[2 * D + t] + red[3 * D + t];
        float val = y[(size_t)n * D + t] + s;
        y[(size_t)n * D + t] = fmaxf(val, 0.f);
    }
}

// ---------------------------------------------------------------- host side
static void run_layer(const float* x, int Fin, const float* W, const float* al,
                      const float* ar, const float* res, const float* ef,
                      const float* vbuf, float* y, int D, float* feat, float* el,
                      float* er, float* den, float* lsorted, const int* src,
                      const int* dst, const int* poe, const int* ssrc,
                      const int* off, hipStream_t stream) {
    int HD = 4 * D;
    dim3 gf(HD / 64, (NN + 63) / 64);
    gemm_f32<<<gf, 256, 0, stream>>>(x, W, feat, NN, HD, Fin);
    dim3 gr(D / 64, (NN + 63) / 64);
    gemm_f32<<<gr, 256, 0, stream>>>(x, res, y, NN, D, Fin);
    if (D == 128) eler_kernel<128><<<NN, 256, 0, stream>>>(feat, al, ar, el, er);
    else          eler_kernel<256><<<NN, 256, 0, stream>>>(feat, al, ar, el, er);
    edge_logit<<<(EE + 255) / 256, 256, 0, stream>>>(el, er, src, dst, ef, vbuf,
                                                     poe, lsorted, EE);
    softmax_seg<<<(NN * 4 + 255) / 256, 256, 0, stream>>>(off, lsorted, den, NN);
    if (D == 128) aggregate<128><<<NN, 256, 0, stream>>>(feat, lsorted, ssrc, off, den, y);
    else          aggregate<256><<<NN, 256, 0, stream>>>(feat, lsorted, ssrc, off, den, y);
}

extern "C" void kernel_launch(void* const* d_in, const int* in_sizes, int n_in,
                              void* d_out, int out_size, void* d_ws, size_t ws_size,
                              hipStream_t stream) {
    const float* node_feats = (const float*)d_in[0];
    const float* edge_feats = (const float*)d_in[1];
    const int*   src        = (const int*)d_in[2];
    const int*   dst        = (const int*)d_in[3];
    const float* W1   = (const float*)d_in[4];
    const float* We1  = (const float*)d_in[5];
    const float* al1  = (const float*)d_in[6];
    const float* ar1  = (const float*)d_in[7];
    const float* ae1  = (const float*)d_in[8];
    const float* res1 = (const float*)d_in[9];
    const float* W2   = (const float*)d_in[10];
    const float* al2  = (const float*)d_in[11];
    const float* ar2  = (const float*)d_in[12];
    const float* res2 = (const float*)d_in[13];
    const float* W3   = (const float*)d_in[14];
    const float* al3  = (const float*)d_in[15];
    const float* ar3  = (const float*)d_in[16];
    const float* res3 = (const float*)d_in[17];
    const float* W4   = (const float*)d_in[18];
    const float* al4  = (const float*)d_in[19];
    const float* ar4  = (const float*)d_in[20];
    const float* res4 = (const float*)d_in[21];

    char* ws = (char*)d_ws;
    auto alloc = [&](size_t bytes) -> char* {
        char* p = ws;
        ws += (bytes + 255) & ~(size_t)255;
        return p;
    };
    int*   counts  = (int*)alloc((size_t)NN * 4);
    int*   offsets = (int*)alloc((size_t)(NN + 1) * 4);
    int*   cursor  = (int*)alloc((size_t)(NN + 1) * 4);
    int*   poe     = (int*)alloc((size_t)EE * 4);
    int*   ssrc    = (int*)alloc((size_t)EE * 4);
    float* feat    = (float*)alloc((size_t)NN * 1024 * 4);
    float* xA      = (float*)alloc((size_t)NN * 128 * 4);
    float* xB      = (float*)alloc((size_t)NN * 128 * 4);
    float* el      = (float*)alloc((size_t)NN * 4 * 4);
    float* er      = (float*)alloc((size_t)NN * 4 * 4);
    float* den     = (float*)alloc((size_t)NN * 4 * 4);
    float* lsorted = (float*)alloc((size_t)EE * 4 * 4);
    float* vbuf    = (float*)alloc(1024);

    // CSR build (identical graph for all 4 layers)
    hipMemsetAsync(counts, 0, (size_t)NN * 4, stream);
    hist_kernel<<<(EE + 255) / 256, 256, 0, stream>>>(dst, counts, EE);
    scan_kernel<<<1, 256, 0, stream>>>(counts, offsets, cursor, NN);
    fill_kernel<<<(EE + 255) / 256, 256, 0, stream>>>(src, dst, cursor, ssrc, poe, EE);

    // layer-1 edge-term collapse: v[i,h] = sum_d We1[i,h,d]*ae1[h,d]
    compute_v<<<1, 256, 0, stream>>>(We1, ae1, vbuf);

    float* out = (float*)d_out;
    run_layer(node_feats, 128, W1, al1, ar1, res1, edge_feats, vbuf, xA, 128,
              feat, el, er, den, lsorted, src, dst, poe, ssrc, offsets, stream);
    run_layer(xA, 128, W2, al2, ar2, res2, nullptr, nullptr, xB, 128,
              feat, el, er, den, lsorted, src, dst, poe, ssrc, offsets, stream);
    run_layer(xB, 128, W3, al3, ar3, res3, nullptr, nullptr, xA, 128,
              feat, el, er, den, lsorted, src, dst, poe, ssrc, offsets, stream);
    run_layer(xA, 128, W4, al4, ar4, res4, nullptr, nullptr, out, 256,
              feat, el, er, den, lsorted, src, dst, poe, ssrc, offsets, stream);
}

// Round 2
// 588.099 us; speedup vs baseline: 1.1946x; 1.1946x over previous
//
#include <hip/hip_runtime.h>

#define NN 10000
#define EE 160000

typedef __attribute__((ext_vector_type(8))) short bf16x8;
typedef __attribute__((ext_vector_type(4))) float f32x4;

__device__ __forceinline__ float b2f(unsigned short s) {
    union { unsigned u; float f; } v; v.u = ((unsigned)s) << 16; return v.f;
}
__device__ __forceinline__ short f2b(float f) {
    union { float f; unsigned u; } v; v.f = f;
    unsigned r = v.u + 0x7FFF + ((v.u >> 16) & 1);  // RNE
    return (short)(r >> 16);
}

// ---------------------------------------------------------------- CSR build
__global__ __launch_bounds__(256) void hist_kernel(const int* __restrict__ dst,
                                                   int* __restrict__ counts, int E) {
    int e = blockIdx.x * 256 + threadIdx.x;
    if (e < E) atomicAdd(&counts[dst[e]], 1);
}

__global__ __launch_bounds__(256) void scan_kernel(const int* __restrict__ counts,
                                                   int* __restrict__ off,
                                                   int* __restrict__ cur, int n) {
    __shared__ int part[256];
    int tid = threadIdx.x;
    int chunk = (n + 255) / 256;
    int lo = tid * chunk; if (lo > n) lo = n;
    int hi = lo + chunk;  if (hi > n) hi = n;
    int s = 0;
    for (int i = lo; i < hi; ++i) s += counts[i];
    part[tid] = s;
    __syncthreads();
    for (int o = 1; o < 256; o <<= 1) {
        int v = (tid >= o) ? part[tid - o] : 0;
        __syncthreads();
        part[tid] += v;
        __syncthreads();
    }
    int run = (tid == 0) ? 0 : part[tid - 1];
    for (int i = lo; i < hi; ++i) { off[i] = run; cur[i] = run; run += counts[i]; }
    if (tid == 255) off[n] = part[255];
}

__global__ __launch_bounds__(256) void fill_kernel(const int* __restrict__ src,
                                                   const int* __restrict__ dst,
                                                   int* __restrict__ cur,
                                                   int* __restrict__ ssrc,
                                                   int* __restrict__ poe, int E) {
    int e = blockIdx.x * 256 + threadIdx.x;
    if (e < E) {
        int p = atomicAdd(&cur[dst[e]], 1);
        ssrc[p] = src[e];
        poe[e] = p;
    }
}

// ---------------------------------------------------------------- casts
__global__ __launch_bounds__(256) void cast_f2b_k(const float* __restrict__ x,
                                                  short* __restrict__ y, int n) {
    int t = blockIdx.x * 256 + threadIdx.x;
    if (t < n) y[t] = f2b(x[t]);
}

// W [128, N] f32 row-major  ->  Wt [N, 128] bf16 row-major (transposed)
__global__ __launch_bounds__(256) void transpose_cast128(const float* __restrict__ W,
                                                         short* __restrict__ Wt, int N) {
    int t = blockIdx.x * 256 + threadIdx.x;
    if (t >= N * 128) return;
    int n = t >> 7, k = t & 127;
    Wt[t] = f2b(W[(size_t)k * N + n]);
}

// ---------------------------------------------------------------- bf16 MFMA GEMM
// C[M,N] = A[M,128] * B[128,N], A bf16 row-major, Bt = B^T bf16 [N,128].
// Block 256 = 4 waves; tile 64(M) x 64(N); wave w -> n-subtile w*16; 4 m-subtiles.
template <bool BF_OUT>
__global__ __launch_bounds__(256) void gemm_mfma(const short* __restrict__ A,
                                                 const short* __restrict__ Bt,
                                                 void* __restrict__ Cv,
                                                 int M, int Ncols) {
    int wave = threadIdx.x >> 6, lane = threadIdx.x & 63;
    int m0 = blockIdx.y * 64;
    int n0 = blockIdx.x * 64 + wave * 16;
    int r = lane & 15, quad = lane >> 4;
    f32x4 acc[4] = {};
    const short* bp = Bt + (size_t)(n0 + r) * 128 + quad * 8;
    #pragma unroll
    for (int k0 = 0; k0 < 128; k0 += 32) {
        bf16x8 bfrag = *(const bf16x8*)(bp + k0);
        #pragma unroll
        for (int mt = 0; mt < 4; ++mt) {
            int gm = m0 + mt * 16 + r;
            bf16x8 afrag = {};
            if (gm < M) afrag = *(const bf16x8*)(A + (size_t)gm * 128 + k0 + quad * 8);
            acc[mt] = __builtin_amdgcn_mfma_f32_16x16x32_bf16(afrag, bfrag, acc[mt], 0, 0, 0);
        }
    }
    int col = n0 + (lane & 15);
    #pragma unroll
    for (int mt = 0; mt < 4; ++mt) {
        #pragma unroll
        for (int rr = 0; rr < 4; ++rr) {
            int gm = m0 + mt * 16 + quad * 4 + rr;
            if (gm < M) {
                float v = acc[mt][rr];
                if constexpr (BF_OUT)
                    ((short*)Cv)[(size_t)gm * Ncols + col] = f2b(v);
                else
                    ((float*)Cv)[(size_t)gm * Ncols + col] = v;
            }
        }
    }
}

// ------------------------------------------------- v[i,h] = sum_d We[i,h,d]*ae[h,d]
__global__ void compute_v(const float* __restrict__ We, const float* __restrict__ ae,
                          float* __restrict__ v) {
    int t = threadIdx.x;        // 256 threads = 64 dims x 4 heads
    int i = t >> 2, h = t & 3;
    const float* w = We + ((size_t)i * 4 + h) * 128;
    const float* a = ae + (size_t)h * 128;
    float s = 0.f;
    for (int d = 0; d < 128; ++d) s += w[d] * a[d];
    v[i * 4 + h] = s;
}

// ------------------------------------------------- el/er from bf16 feat
template <int D>
__global__ __launch_bounds__(256) void eler_bf16(const short* __restrict__ feat,
                                                 const float* __restrict__ al,
                                                 const float* __restrict__ ar,
                                                 float* __restrict__ el,
                                                 float* __restrict__ er) {
    int n = blockIdx.x;
    int h = threadIdx.x >> 6, lane = threadIdx.x & 63;
    constexpr int PER = D / 64;
    const short* f = feat + (size_t)n * (4 * D) + h * D + lane * PER;
    const float* a = al + h * D + lane * PER;
    const float* b = ar + h * D + lane * PER;
    float s1 = 0.f, s2 = 0.f;
    #pragma unroll
    for (int j = 0; j < PER; ++j) {
        float fv = b2f((unsigned short)f[j]);
        s1 += fv * a[j];
        s2 += fv * b[j];
    }
    #pragma unroll
    for (int o = 32; o; o >>= 1) {
        s1 += __shfl_down(s1, o);
        s2 += __shfl_down(s2, o);
    }
    if (lane == 0) { el[n * 4 + h] = s1; er[n * 4 + h] = s2; }
}

// ------------------------------------------------- per-edge logits (leaky relu'd)
__global__ __launch_bounds__(256) void edge_logit(const float* __restrict__ el,
                                                  const float* __restrict__ er,
                                                  const int* __restrict__ src,
                                                  const int* __restrict__ dst,
                                                  const float* __restrict__ ef,
                                                  const float* __restrict__ vbuf,
                                                  const int* __restrict__ poe,
                                                  float* __restrict__ lsorted, int E) {
    __shared__ float vs[256];
    if (ef != nullptr) {
        vs[threadIdx.x] = vbuf[threadIdx.x];
        __syncthreads();
    }
    int e = blockIdx.x * 256 + threadIdx.x;
    if (e >= E) return;
    int s = src[e], d = dst[e];
    float4 elv = *(const float4*)(el + (size_t)s * 4);
    float4 erv = *(const float4*)(er + (size_t)d * 4);
    float a0 = elv.x + erv.x, a1 = elv.y + erv.y, a2 = elv.z + erv.z, a3 = elv.w + erv.w;
    if (ef != nullptr) {
        const float4* e4 = (const float4*)(ef + (size_t)e * 64);
        #pragma unroll
        for (int c = 0; c < 16; ++c) {
            float4 x = e4[c];
            int b = c * 16;
            a0 += x.x * vs[b + 0] + x.y * vs[b + 4] + x.z * vs[b + 8] + x.w * vs[b + 12];
            a1 += x.x * vs[b + 1] + x.y * vs[b + 5] + x.z * vs[b + 9] + x.w * vs[b + 13];
            a2 += x.x * vs[b + 2] + x.y * vs[b + 6] + x.z * vs[b + 10] + x.w * vs[b + 14];
            a3 += x.x * vs[b + 3] + x.y * vs[b + 7] + x.z * vs[b + 11] + x.w * vs[b + 15];
        }
    }
    float4 out;
    out.x = a0 > 0.f ? a0 : 0.2f * a0;
    out.y = a1 > 0.f ? a1 : 0.2f * a1;
    out.z = a2 > 0.f ? a2 : 0.2f * a2;
    out.w = a3 > 0.f ? a3 : 0.2f * a3;
    int p = poe[e];
    *(float4*)(lsorted + (size_t)p * 4) = out;
}

// ------------------------------------------------- segment softmax (in place -> exp)
__global__ __launch_bounds__(256) void softmax_seg(const int* __restrict__ off,
                                                   float* __restrict__ lsorted,
                                                   float* __restrict__ den, int n) {
    int t = blockIdx.x * 256 + threadIdx.x;
    if (t >= n * 4) return;
    int nd = t >> 2, h = t & 3;
    int r0 = off[nd], r1 = off[nd + 1];
    float m = -1e30f;
    for (int p = r0; p < r1; ++p) m = fmaxf(m, lsorted[(size_t)p * 4 + h]);
    float s = 0.f;
    for (int p = r0; p < r1; ++p) {
        float ex = __expf(lsorted[(size_t)p * 4 + h] - m);
        lsorted[(size_t)p * 4 + h] = ex;
        s += ex;
    }
    den[t] = s;
}

// --------------------- aggregation (bf16 gather) + head-mean + residual + ReLU
template <int D>
__global__ __launch_bounds__(256) void aggregate_bf16(const short* __restrict__ feat,
                                                      const float* __restrict__ exs,
                                                      const int* __restrict__ ssrc,
                                                      const int* __restrict__ off,
                                                      const float* __restrict__ den,
                                                      float* __restrict__ y) {
    __shared__ float red[4 * D];
    int n = blockIdx.x;
    int h = threadIdx.x >> 6, lane = threadIdx.x & 63;
    constexpr int PER = D / 64;   // 2 (D=128) or 4 (D=256) bf16 per lane
    float acc[PER] = {};
    int r0 = off[n], r1 = off[n + 1];
    const short* fb = feat + h * D + lane * PER;
    for (int p = r0; p < r1; ++p) {
        float w = exs[(size_t)p * 4 + h];
        const short* f = fb + (size_t)ssrc[p] * (4 * D);
        if constexpr (PER == 2) {
            unsigned v = *(const unsigned*)f;
            acc[0] += w * b2f((unsigned short)(v & 0xFFFF));
            acc[1] += w * b2f((unsigned short)(v >> 16));
        } else {
            uint2 v = *(const uint2*)f;
            acc[0] += w * b2f((unsigned short)(v.x & 0xFFFF));
            acc[1] += w * b2f((unsigned short)(v.x >> 16));
            acc[2] += w * b2f((unsigned short)(v.y & 0xFFFF));
            acc[3] += w * b2f((unsigned short)(v.y >> 16));
        }
    }
    float sc = 0.25f / (den[n * 4 + h] + 1e-9f);
    #pragma unroll
    for (int j = 0; j < PER; ++j) red[h * D + lane * PER + j] = acc[j] * sc;
    __syncthreads();
    for (int t = threadIdx.x; t < D; t += 256) {
        float s = red[t] + red[D + t] + red[2 * D + t] + red[3 * D + t];
        y[(size_t)n * D + t] = fmaxf(y[(size_t)n * D + t] + s, 0.f);
    }
}

// ---------------------------------------------------------------- host side
static void run_layer(const short* xb, const short* Wt, const float* al,
                      const float* ar, const short* resT, const float* ef,
                      const float* vbuf, float* y, int D, short* featb, float* el,
                      float* er, float* den, float* lsorted, const int* src,
                      const int* dst, const int* poe, const int* ssrc,
                      const int* off, hipStream_t stream) {
    int HD = 4 * D;
    dim3 gf(HD / 64, (NN + 63) / 64);
    gemm_mfma<true><<<gf, 256, 0, stream>>>(xb, Wt, featb, NN, HD);
    dim3 gr(D / 64, (NN + 63) / 64);
    gemm_mfma<false><<<gr, 256, 0, stream>>>(xb, resT, y, NN, D);
    if (D == 128) eler_bf16<128><<<NN, 256, 0, stream>>>(featb, al, ar, el, er);
    else          eler_bf16<256><<<NN, 256, 0, stream>>>(featb, al, ar, el, er);
    edge_logit<<<(EE + 255) / 256, 256, 0, stream>>>(el, er, src, dst, ef, vbuf,
                                                     poe, lsorted, EE);
    softmax_seg<<<(NN * 4 + 255) / 256, 256, 0, stream>>>(off, lsorted, den, NN);
    if (D == 128) aggregate_bf16<128><<<NN, 256, 0, stream>>>(featb, lsorted, ssrc, off, den, y);
    else          aggregate_bf16<256><<<NN, 256, 0, stream>>>(featb, lsorted, ssrc, off, den, y);
}

extern "C" void kernel_launch(void* const* d_in, const int* in_sizes, int n_in,
                              void* d_out, int out_size, void* d_ws, size_t ws_size,
                              hipStream_t stream) {
    const float* node_feats = (const float*)d_in[0];
    const float* edge_feats = (const float*)d_in[1];
    const int*   src        = (const int*)d_in[2];
    const int*   dst        = (const int*)d_in[3];
    const float* W1   = (const float*)d_in[4];
    const float* We1  = (const float*)d_in[5];
    const float* al1  = (const float*)d_in[6];
    const float* ar1  = (const float*)d_in[7];
    const float* ae1  = (const float*)d_in[8];
    const float* res1 = (const float*)d_in[9];
    const float* W2   = (const float*)d_in[10];
    const float* al2  = (const float*)d_in[11];
    const float* ar2  = (const float*)d_in[12];
    const float* res2 = (const float*)d_in[13];
    const float* W3   = (const float*)d_in[14];
    const float* al3  = (const float*)d_in[15];
    const float* ar3  = (const float*)d_in[16];
    const float* res3 = (const float*)d_in[17];
    const float* W4   = (const float*)d_in[18];
    const float* al4  = (const float*)d_in[19];
    const float* ar4  = (const float*)d_in[20];
    const float* res4 = (const float*)d_in[21];

    char* ws = (char*)d_ws;
    auto alloc = [&](size_t bytes) -> char* {
        char* p = ws;
        ws += (bytes + 255) & ~(size_t)255;
        return p;
    };
    int*   counts  = (int*)alloc((size_t)NN * 4);
    int*   offsets = (int*)alloc((size_t)(NN + 1) * 4);
    int*   cursor  = (int*)alloc((size_t)(NN + 1) * 4);
    int*   poe     = (int*)alloc((size_t)EE * 4);
    int*   ssrc    = (int*)alloc((size_t)EE * 4);
    short* featb   = (short*)alloc((size_t)NN * 1024 * 2);
    float* xA      = (float*)alloc((size_t)NN * 128 * 4);
    float* xB      = (float*)alloc((size_t)NN * 128 * 4);
    short* xb      = (short*)alloc((size_t)NN * 128 * 2);
    float* el      = (float*)alloc((size_t)NN * 4 * 4);
    float* er      = (float*)alloc((size_t)NN * 4 * 4);
    float* den     = (float*)alloc((size_t)NN * 4 * 4);
    float* lsorted = (float*)alloc((size_t)EE * 4 * 4);
    float* vbuf    = (float*)alloc(1024);
    short* W1t     = (short*)alloc((size_t)512 * 128 * 2);
    short* W2t     = (short*)alloc((size_t)512 * 128 * 2);
    short* W3t     = (short*)alloc((size_t)512 * 128 * 2);
    short* W4t     = (short*)alloc((size_t)1024 * 128 * 2);
    short* r1t     = (short*)alloc((size_t)128 * 128 * 2);
    short* r2t     = (short*)alloc((size_t)128 * 128 * 2);
    short* r3t     = (short*)alloc((size_t)128 * 128 * 2);
    short* r4t     = (short*)alloc((size_t)256 * 128 * 2);

    // CSR build (identical graph for all 4 layers)
    hipMemsetAsync(counts, 0, (size_t)NN * 4, stream);
    hist_kernel<<<(EE + 255) / 256, 256, 0, stream>>>(dst, counts, EE);
    scan_kernel<<<1, 256, 0, stream>>>(counts, offsets, cursor, NN);
    fill_kernel<<<(EE + 255) / 256, 256, 0, stream>>>(src, dst, cursor, ssrc, poe, EE);

    // layer-1 edge-term collapse: v[i,h] = sum_d We1[i,h,d]*ae1[h,d]
    compute_v<<<1, 256, 0, stream>>>(We1, ae1, vbuf);

    // weight conversions (transpose + bf16 cast), all K=128
    transpose_cast128<<<(512 * 128 + 255) / 256, 256, 0, stream>>>(W1, W1t, 512);
    transpose_cast128<<<(512 * 128 + 255) / 256, 256, 0, stream>>>(W2, W2t, 512);
    transpose_cast128<<<(512 * 128 + 255) / 256, 256, 0, stream>>>(W3, W3t, 512);
    transpose_cast128<<<(1024 * 128 + 255) / 256, 256, 0, stream>>>(W4, W4t, 1024);
    transpose_cast128<<<(128 * 128 + 255) / 256, 256, 0, stream>>>(res1, r1t, 128);
    transpose_cast128<<<(128 * 128 + 255) / 256, 256, 0, stream>>>(res2, r2t, 128);
    transpose_cast128<<<(128 * 128 + 255) / 256, 256, 0, stream>>>(res3, r3t, 128);
    transpose_cast128<<<(256 * 128 + 255) / 256, 256, 0, stream>>>(res4, r4t, 256);

    float* out = (float*)d_out;
    const int NX = NN * 128;

    cast_f2b_k<<<(NX + 255) / 256, 256, 0, stream>>>(node_feats, xb, NX);
    run_layer(xb, W1t, al1, ar1, r1t, edge_feats, vbuf, xA, 128,
              featb, el, er, den, lsorted, src, dst, poe, ssrc, offsets, stream);

    cast_f2b_k<<<(NX + 255) / 256, 256, 0, stream>>>(xA, xb, NX);
    run_layer(xb, W2t, al2, ar2, r2t, nullptr, nullptr, xB, 128,
              featb, el, er, den, lsorted, src, dst, poe, ssrc, offsets, stream);

    cast_f2b_k<<<(NX + 255) / 256, 256, 0, stream>>>(xB, xb, NX);
    run_layer(xb, W3t, al3, ar3, r3t, nullptr, nullptr, xA, 128,
              featb, el, er, den, lsorted, src, dst, poe, ssrc, offsets, stream);

    cast_f2b_k<<<(NX + 255) / 256, 256, 0, stream>>>(xA, xb, NX);
    run_layer(xb, W4t, al4, ar4, r4t, nullptr, nullptr, out, 256,
              featb, el, er, den, lsorted, src, dst, poe, ssrc, offsets, stream);
}